// Round 14
// baseline (13.258 us; speedup 1.0000x reference)
//
#include <hip/hip_runtime.h>
#include <math.h>

#define NTOK   1024
#define DMODEL 256
#define NFREQ  128
#define NBINS  48
#define NBH    24             // bins per thread (NBINS/2)
#define DELTA      1.75f      // bin width; 48*1.75 = 84 covers max r (~77)
#define INV_DELTA  0.5714285714285714f
#define INV_4PI_F  0.07957747154594767f
#define INV_2PI_F  0.15915494309189535f
#define LN_EPS_F   1e-5f
#define HSCALE     4194304.0f              // 2^22 fixed-point (exact, deterministic)
#define INV_HSCALE 2.384185791015625e-7f   // 2^-22

typedef __attribute__((ext_vector_type(2))) _Float16 h2;

// One block per target row i (single kernel, no workspace). 256 threads.
// Phase 1: 48-bin x 8-moment histogram, Hp = sum w t^p/p!, t in [-1,1].
//   4 u64 atomics/source (even moment lo-u32 + odd moment hi-i32; even
//   moments nonneg -> no carry into the high field; R13 win).
//   THIS ROUND: TWO histogram copies selected by lane parity — intra-wave
//   same-address serialization (lanes hitting the same hot bin within one
//   ds_atomic instruction) halves, since only same-parity lanes can collide.
//   Integer adds are associative -> still bit-exact/deterministic.
// Phase 2: thread (f=tid&127, h=tid>>7) sweeps bins [24h,24h+24), one
//   broadcast ds_read_b128 per bin, packed-fp16 Horner -> (E,O), 4-FMA
//   rotation recurrence; no trig in any loop. Truncation kap^8/8! <= 6e-4.
// Phase 3: halves combined in LDS, fused LayerNorm.
__global__ __launch_bounds__(256) void wf_ln_kernel(
    const float* __restrict__ coords,       // [N,3]
    const float* __restrict__ wn,           // [NFREQ]
    const float* __restrict__ gamma,        // [DMODEL]
    const float* __restrict__ beta,         // [DMODEL]
    const unsigned char* __restrict__ mask, // [N], nonzero = padded
    float* __restrict__ out)                // [N, DMODEL]
{
    const int i   = blockIdx.x;
    const int tid = threadIdx.x;

    __shared__ unsigned long long Hu[2][4][NBINS]; // [parity][moment-pair][bin]
    __shared__ __align__(16) uint4 Hh[NBINS];      // fp16 x8 per bin, e/o interleaved
    __shared__ float2 comb[NFREQ][2];
    __shared__ float  red[4];

    for (int k = tid; k < 2*4*NBINS; k += 256) ((unsigned long long*)Hu)[k] = 0ULL;
    __syncthreads();

    const float tx = coords[i*3+0];
    const float ty = coords[i*3+1];
    const float tz = coords[i*3+2];

    unsigned long long (* const Hp)[NBINS] = Hu[tid & 1];  // lane-parity copy

    // Phase 1: histogram (4 sources per thread), 4 u64 atomics each.
    for (int j = tid; j < NTOK; j += 256) {
        float dx = coords[j*3+0] - tx;
        float dy = coords[j*3+1] - ty;
        float dz = coords[j*3+2] - tz;
        float d2 = fmaf(dx, dx, fmaf(dy, dy, dz*dz));
        bool valid = (mask[j] == 0) && (d2 > 1e-12f);
        float rinv = rsqrtf(d2);
        float w = valid ? (INV_4PI_F * rinv) : 0.0f;
        float u = valid ? (d2 * rinv * INV_DELTA) : 0.0f;   // r/delta
        int   b = (int)u; b = (b > NBINS-1) ? (NBINS-1) : b;
        float t = fmaf(u - (float)b, 2.0f, -1.0f);          // dr/(delta/2)
        float t2 = t * 0.5f, t3 = t * (1.0f/3.0f), t4 = t * 0.25f;
        float t5 = t * 0.2f, t6 = t * (1.0f/6.0f), t7 = t * (1.0f/7.0f);
        float p0 = w * HSCALE;                              // >= 0
        float p1 = p0 * t;
        float p2 = p1 * t2;                                 // >= 0
        float p3 = p2 * t3;
        float p4 = p3 * t4;                                 // >= 0
        float p5 = p4 * t5;
        float p6 = p5 * t6;                                 // >= 0
        float p7 = p6 * t7;
        unsigned e0 = (unsigned)__float2int_rn(p0);
        unsigned e2 = (unsigned)__float2int_rn(p2);
        unsigned e4 = (unsigned)__float2int_rn(p4);
        unsigned e6 = (unsigned)__float2int_rn(p6);
        unsigned o1 = (unsigned)__float2int_rn(p1);
        unsigned o3 = (unsigned)__float2int_rn(p3);
        unsigned o5 = (unsigned)__float2int_rn(p5);
        unsigned o7 = (unsigned)__float2int_rn(p7);
        atomicAdd(&Hp[0][b], (unsigned long long)e0 | ((unsigned long long)o1 << 32));
        atomicAdd(&Hp[1][b], (unsigned long long)e2 | ((unsigned long long)o3 << 32));
        atomicAdd(&Hp[2][b], (unsigned long long)e4 | ((unsigned long long)o5 << 32));
        atomicAdd(&Hp[3][b], (unsigned long long)e6 | ((unsigned long long)o7 << 32));
    }
    __syncthreads();

    // Phase 1b: merge parity copies, unpack fixed-point -> fp16 x8 per bin.
    if (tid < NBINS) {
        union { _Float16 h[8]; uint4 u; } pk;
        #pragma unroll
        for (int m = 0; m < 4; ++m) {
            unsigned long long q = Hu[0][m][tid] + Hu[1][m][tid];
            int ev = (int)(unsigned)(q & 0xffffffffULL);    // nonneg (no carry)
            int od = (int)(unsigned)(q >> 32);              // wrapped i32
            pk.h[2*m+0] = (_Float16)((float)ev * INV_HSCALE);
            pk.h[2*m+1] = (_Float16)((float)od * INV_HSCALE);
        }
        Hh[tid] = pk.u;
    }
    __syncthreads();

    // Phase 2: packed-Horner recurrence sweep, both trig outputs per thread.
    const int   f    = tid & (NFREQ - 1);
    const int   h    = tid >> 7;              // wave-uniform bin-half selector
    const int   b0   = h * NBH;
    const float kf   = wn[f];
    const float kap  = kf * (0.5f * DELTA);
    const _Float16 mxh = (_Float16)(-kap * kap);
    const h2    mx2  = {mxh, mxh};
    const float rev0 = kf * (((float)b0 + 0.5f) * DELTA) * INV_2PI_F;
    const float revD = kf * DELTA * INV_2PI_F;
    float c  = __builtin_amdgcn_cosf(__builtin_amdgcn_fractf(rev0));
    float s  = __builtin_amdgcn_sinf(__builtin_amdgcn_fractf(rev0));
    const float cD = __builtin_amdgcn_cosf(__builtin_amdgcn_fractf(revD));
    const float sD = __builtin_amdgcn_sinf(__builtin_amdgcn_fractf(revD));

    float accC = 0.0f, accS = 0.0f;
    #pragma unroll 6
    for (int b = b0; b < b0 + NBH; ++b) {
        uint4 raw = Hh[b];                    // broadcast b128: 8 moments
        h2 p01 = __builtin_bit_cast(h2, raw.x);
        h2 p23 = __builtin_bit_cast(h2, raw.y);
        h2 p45 = __builtin_bit_cast(h2, raw.z);
        h2 p67 = __builtin_bit_cast(h2, raw.w);
        h2 eo = p67;
        eo = eo * mx2 + p45;                  // v_pk_fma_f16
        eo = eo * mx2 + p23;
        eo = eo * mx2 + p01;
        float e = (float)eo[0];
        float o = kap * (float)eo[1];
        accC = fmaf(e, c, accC); accC = fmaf(-o, s, accC);
        accS = fmaf(e, s, accS); accS = fmaf( o, c, accS);
        float t1 = s * sD, t2 = c * sD;       // rotate (c,s) by k*delta
        c = fmaf(c, cD, -t1); s = fmaf(s, cD, t2);
    }
    comb[f][h] = make_float2(accC, accS);
    __syncthreads();

    // Feature tid: tid<128 -> cos(real) of freq tid; tid>=128 -> sin(imag).
    float acc = (tid < NFREQ) ? (comb[f][0].x + comb[f][1].x)
                              : (comb[f][0].y + comb[f][1].y);

    // Padded target -> wf row zeroed before LN (LN then yields beta).
    if (mask[i] != 0) acc = 0.0f;

    // Phase 3: fused LayerNorm over the 256 per-thread values.
    const int lane = tid & 63;
    const int wave = tid >> 6;

    float sm = acc;
    #pragma unroll
    for (int off = 32; off > 0; off >>= 1) sm += __shfl_down(sm, off);
    if (lane == 0) red[wave] = sm;
    __syncthreads();
    const float mu = (red[0] + red[1] + red[2] + red[3]) * (1.0f / DMODEL);
    __syncthreads();

    const float d = acc - mu;
    float s2 = d * d;
    #pragma unroll
    for (int off = 32; off > 0; off >>= 1) s2 += __shfl_down(s2, off);
    if (lane == 0) red[wave] = s2;
    __syncthreads();
    const float var  = (red[0] + red[1] + red[2] + red[3]) * (1.0f / DMODEL);
    const float rstd = rsqrtf(var + LN_EPS_F);

    out[i*DMODEL + tid] = d * rstd * gamma[tid] + beta[tid];
}

extern "C" void kernel_launch(void* const* d_in, const int* in_sizes, int n_in,
                              void* d_out, int out_size, void* d_ws, size_t ws_size,
                              hipStream_t stream) {
    const float* coords      = (const float*)d_in[0];
    const float* wavenumbers = (const float*)d_in[1];
    const float* gamma1      = (const float*)d_in[2];
    const float* beta1       = (const float*)d_in[3];
    const unsigned char* kpm = (const unsigned char*)d_in[4];
    float* out = (float*)d_out;

    wf_ln_kernel<<<NTOK, 256, 0, stream>>>(coords, wavenumbers, gamma1, beta1, kpm, out);
}

// Round 15
// 11.565 us; speedup vs baseline: 1.1464x; 1.1464x over previous
//
#include <hip/hip_runtime.h>
#include <math.h>

#define NTOK   1024
#define DMODEL 256
#define NFREQ  128
#define NBINS  48
#define NBP    49             // padded bin stride: parity copies 1568B apart = 8-bank offset
#define NBH    24             // bins per thread (NBINS/2)
#define DELTA      1.75f      // bin width; 48*1.75 = 84 covers max r (~77)
#define INV_DELTA  0.5714285714285714f
#define INV_4PI_F  0.07957747154594767f
#define INV_2PI_F  0.15915494309189535f
#define LN_EPS_F   1e-5f
#define HSCALE     4194304.0f              // 2^22 fixed-point (exact, deterministic)
#define INV_HSCALE 2.384185791015625e-7f   // 2^-22

typedef __attribute__((ext_vector_type(2))) _Float16 h2;

// One block per target row i (single kernel, no workspace). 256 threads.
// Phase 1: 48-bin x 8-moment histogram, Hp = sum w t^p/p!, t in [-1,1].
//   - 4 u64 atomics/source (even lo-u32 + odd hi-i32; even moments nonneg ->
//     no carry; R13-proven).
//   - Parity-split histogram WITH BANK OFFSET (R14 fix): copies at stride
//     4*NBP*8 = 1568B = 392 dwords = 8-bank offset, so opposite-parity lanes
//     hit disjoint banks; hot-bin same-address serialization halves.
//   - Consecutive-j assignment: thread handles j = 4*tid..4*tid+3 -> coord
//     loads become 3x dwordx4 + 1 dword mask (was 12 dword + 4 byte loads).
//   Integer adds associative -> bit-exact/deterministic.
// Phase 2: thread (f=tid&127, h=tid>>7) sweeps bins [24h,24h+24), one
//   broadcast ds_read_b128 per bin, packed-fp16 Horner -> (E,O), 4-FMA
//   rotation recurrence; no trig in any loop. Truncation kap^8/8! <= 6e-4.
// Phase 3: halves combined in LDS, fused LayerNorm.
__global__ __launch_bounds__(256) void wf_ln_kernel(
    const float* __restrict__ coords,       // [N,3]
    const float* __restrict__ wn,           // [NFREQ]
    const float* __restrict__ gamma,        // [DMODEL]
    const float* __restrict__ beta,         // [DMODEL]
    const unsigned char* __restrict__ mask, // [N], nonzero = padded
    float* __restrict__ out)                // [N, DMODEL]
{
    const int i   = blockIdx.x;
    const int tid = threadIdx.x;

    __shared__ unsigned long long Hu[2][4][NBP];  // [parity][moment-pair][bin(padded)]
    __shared__ __align__(16) uint4 Hh[NBINS];     // fp16 x8 per bin, e/o interleaved
    __shared__ float2 comb[NFREQ][2];
    __shared__ float  red[4];

    for (int k = tid; k < 2*4*NBP; k += 256) ((unsigned long long*)Hu)[k] = 0ULL;
    __syncthreads();

    const float tx = coords[i*3+0];
    const float ty = coords[i*3+1];
    const float tz = coords[i*3+2];

    unsigned long long (* const Hp)[NBP] = Hu[tid & 1];   // parity copy (8-bank offset)

    // Phase 1: 4 consecutive sources per thread, vectorized loads.
    const float4* cp4 = (const float4*)coords;            // 48B per thread, 16B-aligned
    float4 c0 = cp4[3*tid+0];
    float4 c1 = cp4[3*tid+1];
    float4 c2 = cp4[3*tid+2];
    const unsigned m4 = *(const unsigned*)(mask + 4*tid); // 4 mask bytes
    const float sx[4] = {c0.x, c0.w, c1.z, c2.y};
    const float sy[4] = {c0.y, c1.x, c1.w, c2.z};
    const float sz[4] = {c0.z, c1.y, c2.x, c2.w};

    #pragma unroll
    for (int jj = 0; jj < 4; ++jj) {
        float dx = sx[jj] - tx;
        float dy = sy[jj] - ty;
        float dz = sz[jj] - tz;
        float d2 = fmaf(dx, dx, fmaf(dy, dy, dz*dz));
        bool valid = (((m4 >> (8*jj)) & 0xffu) == 0) && (d2 > 1e-12f);
        float rinv = rsqrtf(d2);
        float w = valid ? (INV_4PI_F * rinv) : 0.0f;
        float u = valid ? (d2 * rinv * INV_DELTA) : 0.0f;   // r/delta
        int   b = (int)u; b = (b > NBINS-1) ? (NBINS-1) : b;
        float t = fmaf(u - (float)b, 2.0f, -1.0f);          // dr/(delta/2)
        float t2 = t * 0.5f, t3 = t * (1.0f/3.0f), t4 = t * 0.25f;
        float t5 = t * 0.2f, t6 = t * (1.0f/6.0f), t7 = t * (1.0f/7.0f);
        float p0 = w * HSCALE;                              // >= 0
        float p1 = p0 * t;
        float p2 = p1 * t2;                                 // >= 0
        float p3 = p2 * t3;
        float p4 = p3 * t4;                                 // >= 0
        float p5 = p4 * t5;
        float p6 = p5 * t6;                                 // >= 0
        float p7 = p6 * t7;
        unsigned e0 = (unsigned)__float2int_rn(p0);
        unsigned e2 = (unsigned)__float2int_rn(p2);
        unsigned e4 = (unsigned)__float2int_rn(p4);
        unsigned e6 = (unsigned)__float2int_rn(p6);
        unsigned o1 = (unsigned)__float2int_rn(p1);
        unsigned o3 = (unsigned)__float2int_rn(p3);
        unsigned o5 = (unsigned)__float2int_rn(p5);
        unsigned o7 = (unsigned)__float2int_rn(p7);
        atomicAdd(&Hp[0][b], (unsigned long long)e0 | ((unsigned long long)o1 << 32));
        atomicAdd(&Hp[1][b], (unsigned long long)e2 | ((unsigned long long)o3 << 32));
        atomicAdd(&Hp[2][b], (unsigned long long)e4 | ((unsigned long long)o5 << 32));
        atomicAdd(&Hp[3][b], (unsigned long long)e6 | ((unsigned long long)o7 << 32));
    }
    __syncthreads();

    // Phase 1b: merge parity copies, unpack fixed-point -> fp16 x8 per bin.
    if (tid < NBINS) {
        union { _Float16 h[8]; uint4 u; } pk;
        #pragma unroll
        for (int m = 0; m < 4; ++m) {
            unsigned long long q = Hu[0][m][tid] + Hu[1][m][tid];
            int ev = (int)(unsigned)(q & 0xffffffffULL);    // nonneg (no carry)
            int od = (int)(unsigned)(q >> 32);              // wrapped i32
            pk.h[2*m+0] = (_Float16)((float)ev * INV_HSCALE);
            pk.h[2*m+1] = (_Float16)((float)od * INV_HSCALE);
        }
        Hh[tid] = pk.u;
    }
    __syncthreads();

    // Phase 2: packed-Horner recurrence sweep, both trig outputs per thread.
    const int   f    = tid & (NFREQ - 1);
    const int   h    = tid >> 7;              // wave-uniform bin-half selector
    const int   b0   = h * NBH;
    const float kf   = wn[f];
    const float kap  = kf * (0.5f * DELTA);
    const _Float16 mxh = (_Float16)(-kap * kap);
    const h2    mx2  = {mxh, mxh};
    const float rev0 = kf * (((float)b0 + 0.5f) * DELTA) * INV_2PI_F;
    const float revD = kf * DELTA * INV_2PI_F;
    float c  = __builtin_amdgcn_cosf(__builtin_amdgcn_fractf(rev0));
    float s  = __builtin_amdgcn_sinf(__builtin_amdgcn_fractf(rev0));
    const float cD = __builtin_amdgcn_cosf(__builtin_amdgcn_fractf(revD));
    const float sD = __builtin_amdgcn_sinf(__builtin_amdgcn_fractf(revD));

    float accC = 0.0f, accS = 0.0f;
    #pragma unroll 6
    for (int b = b0; b < b0 + NBH; ++b) {
        uint4 raw = Hh[b];                    // broadcast b128: 8 moments
        h2 p01 = __builtin_bit_cast(h2, raw.x);
        h2 p23 = __builtin_bit_cast(h2, raw.y);
        h2 p45 = __builtin_bit_cast(h2, raw.z);
        h2 p67 = __builtin_bit_cast(h2, raw.w);
        h2 eo = p67;
        eo = eo * mx2 + p45;                  // v_pk_fma_f16
        eo = eo * mx2 + p23;
        eo = eo * mx2 + p01;
        float e = (float)eo[0];
        float o = kap * (float)eo[1];
        accC = fmaf(e, c, accC); accC = fmaf(-o, s, accC);
        accS = fmaf(e, s, accS); accS = fmaf( o, c, accS);
        float t1 = s * sD, t2 = c * sD;       // rotate (c,s) by k*delta
        c = fmaf(c, cD, -t1); s = fmaf(s, cD, t2);
    }
    comb[f][h] = make_float2(accC, accS);
    __syncthreads();

    // Feature tid: tid<128 -> cos(real) of freq tid; tid>=128 -> sin(imag).
    float acc = (tid < NFREQ) ? (comb[f][0].x + comb[f][1].x)
                              : (comb[f][0].y + comb[f][1].y);

    // Padded target -> wf row zeroed before LN (LN then yields beta).
    if (mask[i] != 0) acc = 0.0f;

    // Phase 3: fused LayerNorm over the 256 per-thread values.
    const int lane = tid & 63;
    const int wave = tid >> 6;

    float sm = acc;
    #pragma unroll
    for (int off = 32; off > 0; off >>= 1) sm += __shfl_down(sm, off);
    if (lane == 0) red[wave] = sm;
    __syncthreads();
    const float mu = (red[0] + red[1] + red[2] + red[3]) * (1.0f / DMODEL);
    __syncthreads();

    const float d = acc - mu;
    float s2 = d * d;
    #pragma unroll
    for (int off = 32; off > 0; off >>= 1) s2 += __shfl_down(s2, off);
    if (lane == 0) red[wave] = s2;
    __syncthreads();
    const float var  = (red[0] + red[1] + red[2] + red[3]) * (1.0f / DMODEL);
    const float rstd = rsqrtf(var + LN_EPS_F);

    out[i*DMODEL + tid] = d * rstd * gamma[tid] + beta[tid];
}

extern "C" void kernel_launch(void* const* d_in, const int* in_sizes, int n_in,
                              void* d_out, int out_size, void* d_ws, size_t ws_size,
                              hipStream_t stream) {
    const float* coords      = (const float*)d_in[0];
    const float* wavenumbers = (const float*)d_in[1];
    const float* gamma1      = (const float*)d_in[2];
    const float* beta1       = (const float*)d_in[3];
    const unsigned char* kpm = (const unsigned char*)d_in[4];
    float* out = (float*)d_out;

    wf_ln_kernel<<<NTOK, 256, 0, stream>>>(coords, wavenumbers, gamma1, beta1, kpm, out);
}

// Round 16
// 11.415 us; speedup vs baseline: 1.1614x; 1.0131x over previous
//
#include <hip/hip_runtime.h>
#include <math.h>

#define NTOK   1024
#define DMODEL 256
#define NFREQ  128
#define NBINS  48
#define NBP    49             // padded bin stride: copies 1568B apart = 8-bank offsets
#define NBH    24             // bins per thread (NBINS/2)
#define DELTA      1.75f      // bin width; 48*1.75 = 84 covers max r (~77)
#define INV_DELTA  0.5714285714285714f
#define INV_4PI_F  0.07957747154594767f
#define INV_2PI_F  0.15915494309189535f
#define LN_EPS_F   1e-5f
#define HSCALE     4194304.0f              // 2^22 fixed-point (exact, deterministic)
#define INV_HSCALE 2.384185791015625e-7f   // 2^-22

typedef __attribute__((ext_vector_type(2))) _Float16 h2;

// One block per target row i (single kernel, no workspace). 256 threads.
// Phase 1: 48-bin x 8-moment histogram, Hp = sum w t^p/p!, t in [-1,1].
//   - 4 u64 atomics/source (even lo-u32 + odd hi-i32; even moments nonneg ->
//     no carry; R13-proven).
//   - FOUR parity copies (tid&3) at 8-bank offsets {0,8,16,24} (R15's 2-way
//     split paid -0.4us; Gaussian r concentrates sources in few hot bins, so
//     same-parity lanes still collided ~2-way; this cuts multiplicity ~1.2x).
//   - Consecutive-j vectorized loads: 3x dwordx4 + 1 dword per thread.
//   Integer adds associative -> bit-exact/deterministic.
// Phase 2: thread (f=tid&127, h=tid>>7) sweeps bins [24h,24h+24), one
//   broadcast ds_read_b128 per bin, packed-fp16 Horner -> (E,O), 4-FMA
//   rotation recurrence; no trig in any loop. Truncation kap^8/8! <= 6e-4.
// Phase 3: halves combined in LDS, fused LayerNorm.
__global__ __launch_bounds__(256) void wf_ln_kernel(
    const float* __restrict__ coords,       // [N,3]
    const float* __restrict__ wn,           // [NFREQ]
    const float* __restrict__ gamma,        // [DMODEL]
    const float* __restrict__ beta,         // [DMODEL]
    const unsigned char* __restrict__ mask, // [N], nonzero = padded
    float* __restrict__ out)                // [N, DMODEL]
{
    const int i   = blockIdx.x;
    const int tid = threadIdx.x;

    __shared__ unsigned long long Hu[4][4][NBP];  // [parity][moment-pair][bin(padded)]
    __shared__ __align__(16) uint4 Hh[NBINS];     // fp16 x8 per bin, e/o interleaved
    __shared__ float2 comb[NFREQ][2];
    __shared__ float  red[4];

    for (int k = tid; k < 4*4*NBP; k += 256) ((unsigned long long*)Hu)[k] = 0ULL;
    __syncthreads();

    const float tx = coords[i*3+0];
    const float ty = coords[i*3+1];
    const float tz = coords[i*3+2];

    unsigned long long (* const Hp)[NBP] = Hu[tid & 3];   // parity copy (8-bank offsets)

    // Phase 1: 4 consecutive sources per thread, vectorized loads.
    const float4* cp4 = (const float4*)coords;            // 48B per thread, 16B-aligned
    float4 c0 = cp4[3*tid+0];
    float4 c1 = cp4[3*tid+1];
    float4 c2 = cp4[3*tid+2];
    const unsigned m4 = *(const unsigned*)(mask + 4*tid); // 4 mask bytes
    const float sx[4] = {c0.x, c0.w, c1.z, c2.y};
    const float sy[4] = {c0.y, c1.x, c1.w, c2.z};
    const float sz[4] = {c0.z, c1.y, c2.x, c2.w};

    #pragma unroll
    for (int jj = 0; jj < 4; ++jj) {
        float dx = sx[jj] - tx;
        float dy = sy[jj] - ty;
        float dz = sz[jj] - tz;
        float d2 = fmaf(dx, dx, fmaf(dy, dy, dz*dz));
        bool valid = (((m4 >> (8*jj)) & 0xffu) == 0) && (d2 > 1e-12f);
        float rinv = rsqrtf(d2);
        float w = valid ? (INV_4PI_F * rinv) : 0.0f;
        float u = valid ? (d2 * rinv * INV_DELTA) : 0.0f;   // r/delta
        int   b = (int)u; b = (b > NBINS-1) ? (NBINS-1) : b;
        float t = fmaf(u - (float)b, 2.0f, -1.0f);          // dr/(delta/2)
        float t2 = t * 0.5f, t3 = t * (1.0f/3.0f), t4 = t * 0.25f;
        float t5 = t * 0.2f, t6 = t * (1.0f/6.0f), t7 = t * (1.0f/7.0f);
        float p0 = w * HSCALE;                              // >= 0
        float p1 = p0 * t;
        float p2 = p1 * t2;                                 // >= 0
        float p3 = p2 * t3;
        float p4 = p3 * t4;                                 // >= 0
        float p5 = p4 * t5;
        float p6 = p5 * t6;                                 // >= 0
        float p7 = p6 * t7;
        unsigned e0 = (unsigned)__float2int_rn(p0);
        unsigned e2 = (unsigned)__float2int_rn(p2);
        unsigned e4 = (unsigned)__float2int_rn(p4);
        unsigned e6 = (unsigned)__float2int_rn(p6);
        unsigned o1 = (unsigned)__float2int_rn(p1);
        unsigned o3 = (unsigned)__float2int_rn(p3);
        unsigned o5 = (unsigned)__float2int_rn(p5);
        unsigned o7 = (unsigned)__float2int_rn(p7);
        atomicAdd(&Hp[0][b], (unsigned long long)e0 | ((unsigned long long)o1 << 32));
        atomicAdd(&Hp[1][b], (unsigned long long)e2 | ((unsigned long long)o3 << 32));
        atomicAdd(&Hp[2][b], (unsigned long long)e4 | ((unsigned long long)o5 << 32));
        atomicAdd(&Hp[3][b], (unsigned long long)e6 | ((unsigned long long)o7 << 32));
    }
    __syncthreads();

    // Phase 1b: merge 4 parity copies, unpack fixed-point -> fp16 x8 per bin.
    if (tid < NBINS) {
        union { _Float16 h[8]; uint4 u; } pk;
        #pragma unroll
        for (int m = 0; m < 4; ++m) {
            unsigned long long q = (Hu[0][m][tid] + Hu[1][m][tid])
                                 + (Hu[2][m][tid] + Hu[3][m][tid]);
            int ev = (int)(unsigned)(q & 0xffffffffULL);    // nonneg (no carry)
            int od = (int)(unsigned)(q >> 32);              // wrapped i32
            pk.h[2*m+0] = (_Float16)((float)ev * INV_HSCALE);
            pk.h[2*m+1] = (_Float16)((float)od * INV_HSCALE);
        }
        Hh[tid] = pk.u;
    }
    __syncthreads();

    // Phase 2: packed-Horner recurrence sweep, both trig outputs per thread.
    const int   f    = tid & (NFREQ - 1);
    const int   h    = tid >> 7;              // wave-uniform bin-half selector
    const int   b0   = h * NBH;
    const float kf   = wn[f];
    const float kap  = kf * (0.5f * DELTA);
    const _Float16 mxh = (_Float16)(-kap * kap);
    const h2    mx2  = {mxh, mxh};
    const float rev0 = kf * (((float)b0 + 0.5f) * DELTA) * INV_2PI_F;
    const float revD = kf * DELTA * INV_2PI_F;
    float c  = __builtin_amdgcn_cosf(__builtin_amdgcn_fractf(rev0));
    float s  = __builtin_amdgcn_sinf(__builtin_amdgcn_fractf(rev0));
    const float cD = __builtin_amdgcn_cosf(__builtin_amdgcn_fractf(revD));
    const float sD = __builtin_amdgcn_sinf(__builtin_amdgcn_fractf(revD));

    float accC = 0.0f, accS = 0.0f;
    #pragma unroll 6
    for (int b = b0; b < b0 + NBH; ++b) {
        uint4 raw = Hh[b];                    // broadcast b128: 8 moments
        h2 p01 = __builtin_bit_cast(h2, raw.x);
        h2 p23 = __builtin_bit_cast(h2, raw.y);
        h2 p45 = __builtin_bit_cast(h2, raw.z);
        h2 p67 = __builtin_bit_cast(h2, raw.w);
        h2 eo = p67;
        eo = eo * mx2 + p45;                  // v_pk_fma_f16
        eo = eo * mx2 + p23;
        eo = eo * mx2 + p01;
        float e = (float)eo[0];
        float o = kap * (float)eo[1];
        accC = fmaf(e, c, accC); accC = fmaf(-o, s, accC);
        accS = fmaf(e, s, accS); accS = fmaf( o, c, accS);
        float t1 = s * sD, t2 = c * sD;       // rotate (c,s) by k*delta
        c = fmaf(c, cD, -t1); s = fmaf(s, cD, t2);
    }
    comb[f][h] = make_float2(accC, accS);
    __syncthreads();

    // Feature tid: tid<128 -> cos(real) of freq tid; tid>=128 -> sin(imag).
    float acc = (tid < NFREQ) ? (comb[f][0].x + comb[f][1].x)
                              : (comb[f][0].y + comb[f][1].y);

    // Padded target -> wf row zeroed before LN (LN then yields beta).
    if (mask[i] != 0) acc = 0.0f;

    // Phase 3: fused LayerNorm over the 256 per-thread values.
    const int lane = tid & 63;
    const int wave = tid >> 6;

    float sm = acc;
    #pragma unroll
    for (int off = 32; off > 0; off >>= 1) sm += __shfl_down(sm, off);
    if (lane == 0) red[wave] = sm;
    __syncthreads();
    const float mu = (red[0] + red[1] + red[2] + red[3]) * (1.0f / DMODEL);
    __syncthreads();

    const float d = acc - mu;
    float s2 = d * d;
    #pragma unroll
    for (int off = 32; off > 0; off >>= 1) s2 += __shfl_down(s2, off);
    if (lane == 0) red[wave] = s2;
    __syncthreads();
    const float var  = (red[0] + red[1] + red[2] + red[3]) * (1.0f / DMODEL);
    const float rstd = rsqrtf(var + LN_EPS_F);

    out[i*DMODEL + tid] = d * rstd * gamma[tid] + beta[tid];
}

extern "C" void kernel_launch(void* const* d_in, const int* in_sizes, int n_in,
                              void* d_out, int out_size, void* d_ws, size_t ws_size,
                              hipStream_t stream) {
    const float* coords      = (const float*)d_in[0];
    const float* wavenumbers = (const float*)d_in[1];
    const float* gamma1      = (const float*)d_in[2];
    const float* beta1       = (const float*)d_in[3];
    const unsigned char* kpm = (const unsigned char*)d_in[4];
    float* out = (float*)d_out;

    wf_ln_kernel<<<NTOK, 256, 0, stream>>>(coords, wavenumbers, gamma1, beta1, kpm, out);
}